// Round 6
// baseline (379.448 us; speedup 1.0000x reference)
//
#include <hip/hip_runtime.h>
#include <math.h>

#define NODE_DIM 32
#define EDGE_DIM 16
#define WPC 64           // edges per wave-chunk
#define MAXBLK 2500      // 2500 blk x 4 waves x 64 edges = 640K edges/pass; 3.2M = 5 passes exactly

typedef __attribute__((ext_vector_type(8))) short bf16x8;
typedef __attribute__((ext_vector_type(4))) float f32x4;

__device__ __forceinline__ short f2bf(float f) {
    union { float f; unsigned u; } v; v.f = f;
    unsigned r = v.u + 0x7FFFu + ((v.u >> 16) & 1u);   // round-nearest-even
    return (short)(r >> 16);
}

__device__ __forceinline__ float fast_sigmoid(float v) {
    return __builtin_amdgcn_rcpf(1.0f + __expf(-v));
}
__device__ __forceinline__ float fast_softplus(float v) {
    float t = __expf(-fabsf(v));
    return fmaxf(v, 0.0f) + __logf(1.0f + t);
}

// prologue: x (f32, [N][32]) -> xb (bf16, [N][32]); one thread per 8 elems
__global__ __launch_bounds__(256) void xconv_kernel(
    const float* __restrict__ x, short* __restrict__ xb, int ngroups)
{
    const int i = blockIdx.x * 256 + threadIdx.x;
    if (i >= ngroups) return;
    const float4* p = (const float4*)x + 2 * (size_t)i;
    float4 u0 = p[0], u1 = p[1];
    bf16x8 o;
    o[0]=f2bf(u0.x); o[1]=f2bf(u0.y); o[2]=f2bf(u0.z); o[3]=f2bf(u0.w);
    o[4]=f2bf(u1.x); o[5]=f2bf(u1.y); o[6]=f2bf(u1.z); o[7]=f2bf(u1.w);
    ((bf16x8*)xb)[i] = o;
}

// Barrier-free, LDS-free edge kernel. Each wave owns independent 64-edge
// chunks; cross-lane meta moves via __shfl (register-sourced, no sync needed).
__global__ __launch_bounds__(256, 4) void edge_kernel(
    const short* __restrict__ xb,   // bf16 node features
    const int*   __restrict__ ei,
    const float* __restrict__ ea,
    const float* __restrict__ ew,
    const float* __restrict__ Wf,
    const float* __restrict__ bfb,
    const float* __restrict__ Ws,
    const float* __restrict__ bsb,
    float* __restrict__ agg,
    float* __restrict__ out_ei,   // harness reads whole d_out as f32
    float* __restrict__ out_ea,
    float* __restrict__ out_ew,
    int E)
{
    const int tid  = threadIdx.x;
    const int lane = tid & 63;
    const int wave = tid >> 6;
    const int kg   = lane >> 4;    // 0..3: k-slice group (8 bf16 each)
    const int c16  = lane & 15;    // fragment row/col index

    // ---- B fragments: Wcomb[96][64] (cols 0-31 = Wf, 32-63 = Ws; k>=80 zero) ----
    // lane holds B[k = 32m + 8*kg + j][col = 16*ct + c16], j=0..7
    bf16x8 Bf[3][4];
    float biasv[4];
    #pragma unroll
    for (int ct = 0; ct < 4; ++ct) {
        const int cc = ct * 16 + c16;              // 0..63
        const float* Wsrc = (cc < 32) ? Wf  : Ws;
        const float* bsrc = (cc < 32) ? bfb : bsb;
        const int ccc = cc & 31;
        biasv[ct] = bsrc[ccc];
        #pragma unroll
        for (int m = 0; m < 3; ++m) {
            bf16x8 frag;
            #pragma unroll
            for (int j = 0; j < 8; ++j) {
                const int k = 32 * m + 8 * kg + j;
                const float wv = (k < 80) ? Wsrc[k * NODE_DIM + ccc] : 0.0f;
                frag[j] = f2bf(wv);
            }
            Bf[m][ct] = frag;
        }
    }

    const int wid    = blockIdx.x * 4 + wave;
    const int nwaves = gridDim.x * 4;

    for (int base = wid * WPC; base < E; base += nwaves * WPC) {
        // ---- per-wave phase 1: meta into registers + passthrough ----
        const int e0 = base + lane;
        int srcv = 0, dstv = -1; float wv = 0.0f;
        if (e0 < E) {
            srcv = ei[e0];
            dstv = ei[E + e0];
            wv   = ew[e0];
            out_ei[e0]     = (float)srcv;
            out_ei[E + e0] = (float)dstv;
            out_ew[e0]     = wv;
        }
        // ea passthrough: 64 edges * 16 f32 = 256 float4, coalesced per wave
        {
            const float4* s4 = (const float4*)ea;
            float4*       d4 = (float4*)out_ea;
            const int fmax = E * 4;          // total float4 count (E*16 floats)
            const int fb   = base * 4;
            #pragma unroll
            for (int t = 0; t < 4; ++t) {
                const int idx = fb + t * 64 + lane;
                if (idx < fmax) d4[idx] = s4[idx];
            }
        }

        // ---- per-wave phase 2: 4 groups of 16 edges; MFMA z@[Wf|Ws] ----
        #pragma unroll 2
        for (int g = 0; g < 4; ++g) {
            const int sA   = g * 16 + c16;                 // A row m = c16
            const int dstn = max(__shfl(dstv, sA), 0);
            const int srcn = max(__shfl(srcv, sA), 0);

            // A0: z[0..31] = x[dst]; lane covers k = 8*kg..+7 (one 16B load)
            bf16x8 a0 = *(const bf16x8*)(xb + (size_t)dstn * NODE_DIM + 8 * kg);
            // A1: z[32..63] = x[src]
            bf16x8 a1 = *(const bf16x8*)(xb + (size_t)srcn * NODE_DIM + 8 * kg);
            // A2: z[64..95] = edge_attr | zero pad (re-read, L1/L2-hot)
            bf16x8 a2 = {0,0,0,0,0,0,0,0};
            if (kg < 2) {
                int eidx = base + sA; if (eidx >= E) eidx = E - 1;
                const float4* p = (const float4*)(ea + (size_t)eidx * EDGE_DIM + 8 * kg);
                float4 u0 = p[0], u1 = p[1];
                a2[0]=f2bf(u0.x); a2[1]=f2bf(u0.y); a2[2]=f2bf(u0.z); a2[3]=f2bf(u0.w);
                a2[4]=f2bf(u1.x); a2[5]=f2bf(u1.y); a2[6]=f2bf(u1.z); a2[7]=f2bf(u1.w);
            }

            f32x4 acc0 = {biasv[0], biasv[0], biasv[0], biasv[0]};
            f32x4 acc1 = {biasv[1], biasv[1], biasv[1], biasv[1]};
            f32x4 acc2 = {biasv[2], biasv[2], biasv[2], biasv[2]};
            f32x4 acc3 = {biasv[3], biasv[3], biasv[3], biasv[3]};

            acc0 = __builtin_amdgcn_mfma_f32_16x16x32_bf16(a0, Bf[0][0], acc0, 0, 0, 0);
            acc1 = __builtin_amdgcn_mfma_f32_16x16x32_bf16(a0, Bf[0][1], acc1, 0, 0, 0);
            acc2 = __builtin_amdgcn_mfma_f32_16x16x32_bf16(a0, Bf[0][2], acc2, 0, 0, 0);
            acc3 = __builtin_amdgcn_mfma_f32_16x16x32_bf16(a0, Bf[0][3], acc3, 0, 0, 0);
            acc0 = __builtin_amdgcn_mfma_f32_16x16x32_bf16(a1, Bf[1][0], acc0, 0, 0, 0);
            acc1 = __builtin_amdgcn_mfma_f32_16x16x32_bf16(a1, Bf[1][1], acc1, 0, 0, 0);
            acc2 = __builtin_amdgcn_mfma_f32_16x16x32_bf16(a1, Bf[1][2], acc2, 0, 0, 0);
            acc3 = __builtin_amdgcn_mfma_f32_16x16x32_bf16(a1, Bf[1][3], acc3, 0, 0, 0);
            acc0 = __builtin_amdgcn_mfma_f32_16x16x32_bf16(a2, Bf[2][0], acc0, 0, 0, 0);
            acc1 = __builtin_amdgcn_mfma_f32_16x16x32_bf16(a2, Bf[2][1], acc1, 0, 0, 0);
            acc2 = __builtin_amdgcn_mfma_f32_16x16x32_bf16(a2, Bf[2][2], acc2, 0, 0, 0);
            acc3 = __builtin_amdgcn_mfma_f32_16x16x32_bf16(a2, Bf[2][3], acc3, 0, 0, 0);

            // C/D: col = c16 (+16 per ct), row = kg*4 + r (rows = edges);
            // gate col c and val col c live in the SAME lane (ct0/ct2, ct1/ct3)
            const int rb = g * 16 + (kg << 2);
            #pragma unroll
            for (int r = 0; r < 4; ++r) {
                const int slot = rb + r;
                const int d    = __shfl(dstv, slot);
                const float w  = __shfl(wv,   slot);
                const float m0 = w * fast_sigmoid(acc0[r]) * fast_softplus(acc2[r]);
                const float m1 = w * fast_sigmoid(acc1[r]) * fast_softplus(acc3[r]);
                if (d >= 0) {
                    unsafeAtomicAdd(&agg[(size_t)d * NODE_DIM + c16],      m0);
                    unsafeAtomicAdd(&agg[(size_t)d * NODE_DIM + 16 + c16], m1);
                }
            }
        }
    }
}

__global__ __launch_bounds__(256) void node_kernel(
    const float* __restrict__ x,
    const float* __restrict__ agg,
    const float* __restrict__ ln_g,
    const float* __restrict__ ln_b,
    const float* __restrict__ W,
    const float* __restrict__ b,
    float* __restrict__ out,
    int N)
{
    const int n = blockIdx.x * blockDim.x + threadIdx.x;
    if (n >= N) return;

    float xr[NODE_DIM], h[NODE_DIM];
    const float4* xp = (const float4*)(x   + (size_t)n * NODE_DIM);
    const float4* ap = (const float4*)(agg + (size_t)n * NODE_DIM);

    float s = 0.0f, ss = 0.0f;
    #pragma unroll
    for (int i = 0; i < 8; ++i) {
        float4 xv = xp[i];
        float4 av = ap[i];
        float hv0 = xv.x + av.x, hv1 = xv.y + av.y, hv2 = xv.z + av.z, hv3 = xv.w + av.w;
        xr[4*i+0] = xv.x; xr[4*i+1] = xv.y; xr[4*i+2] = xv.z; xr[4*i+3] = xv.w;
        h[4*i+0] = hv0; h[4*i+1] = hv1; h[4*i+2] = hv2; h[4*i+3] = hv3;
        s  += hv0 + hv1 + hv2 + hv3;
        ss += hv0*hv0 + hv1*hv1 + hv2*hv2 + hv3*hv3;
    }

    const float mu  = s * (1.0f / NODE_DIM);
    float var = ss * (1.0f / NODE_DIM) - mu * mu;
    var = fmaxf(var, 0.0f);
    const float rstd = __builtin_amdgcn_rsqf(var + 1e-5f);

    float acc[NODE_DIM];
    #pragma unroll
    for (int j = 0; j < NODE_DIM; ++j) acc[j] = b[j] + xr[j];

    #pragma unroll
    for (int k = 0; k < NODE_DIM; ++k) {
        float hn = (h[k] - mu) * rstd * ln_g[k] + ln_b[k];
        #pragma unroll
        for (int j = 0; j < NODE_DIM; ++j) {
            acc[j] = fmaf(hn, W[k * NODE_DIM + j], acc[j]);
        }
    }

    float4* op = (float4*)(out + (size_t)n * NODE_DIM);
    #pragma unroll
    for (int i = 0; i < 8; ++i) {
        float4 o;
        float a0 = acc[4*i+0], a1 = acc[4*i+1], a2 = acc[4*i+2], a3 = acc[4*i+3];
        o.x = (a0 > 0.0f) ? a0 : (__expf(a0) - 1.0f);
        o.y = (a1 > 0.0f) ? a1 : (__expf(a1) - 1.0f);
        o.z = (a2 > 0.0f) ? a2 : (__expf(a2) - 1.0f);
        o.w = (a3 > 0.0f) ? a3 : (__expf(a3) - 1.0f);
        op[i] = o;
    }
}

extern "C" void kernel_launch(void* const* d_in, const int* in_sizes, int n_in,
                              void* d_out, int out_size, void* d_ws, size_t ws_size,
                              hipStream_t stream)
{
    const float* x   = (const float*)d_in[0];
    const int*   ei  = (const int*)  d_in[1];
    const float* ea  = (const float*)d_in[2];
    const float* ew  = (const float*)d_in[3];
    const float* Wf  = (const float*)d_in[4];
    const float* bf  = (const float*)d_in[5];
    const float* Ws  = (const float*)d_in[6];
    const float* bs  = (const float*)d_in[7];
    const float* lg  = (const float*)d_in[8];
    const float* lb  = (const float*)d_in[9];
    const float* W   = (const float*)d_in[10];
    const float* b   = (const float*)d_in[11];

    const int E = in_sizes[3];              // N_EDGES
    const int N = in_sizes[0] / NODE_DIM;   // N_NODES

    float* out    = (float*)d_out;
    float* out_x  = out;
    float* out_ei = out + (size_t)N * NODE_DIM;
    float* out_ea = out + (size_t)N * NODE_DIM + 2 * (size_t)E;
    float* out_ew = out_ea + (size_t)E * EDGE_DIM;

    // workspace layout: agg (N*32 f32 = 12.8 MB) | xb (N*32 bf16 = 6.4 MB)
    float* agg = (float*)d_ws;
    short* xbuf = (short*)((char*)d_ws + (size_t)N * NODE_DIM * sizeof(float));

    hipMemsetAsync(agg, 0, (size_t)N * NODE_DIM * sizeof(float), stream);

    const int ngroups = N * NODE_DIM / 8;
    xconv_kernel<<<dim3((ngroups + 255) / 256), dim3(256), 0, stream>>>(x, xbuf, ngroups);

    int nblk = (E + 4 * WPC - 1) / (4 * WPC);
    if (nblk > MAXBLK) nblk = MAXBLK;
    edge_kernel<<<dim3(nblk), dim3(256), 0, stream>>>(
        xbuf, ei, ea, ew, Wf, bf, Ws, bs, agg, out_ei, out_ea, out_ew, E);

    dim3 nb(256), ng((N + 255) / 256);
    node_kernel<<<ng, nb, 0, stream>>>(x, agg, lg, lb, W, b, out_x, N);
}

// Round 7
// 281.345 us; speedup vs baseline: 1.3487x; 1.3487x over previous
//
#include <hip/hip_runtime.h>
#include <hip/hip_fp16.h>
#include <math.h>

#define NODE_DIM 32
#define EDGE_DIM 16
#define WPC 64           // edges per wave-chunk
#define MAXBLK 2500      // 2500 blk x 4 waves x 64 edges = 640K edges/pass

typedef __attribute__((ext_vector_type(8))) short bf16x8;
typedef __attribute__((ext_vector_type(4))) short short4v;
typedef __attribute__((ext_vector_type(4))) float f32x4;

__device__ __forceinline__ short f2bf(float f) {
    union { float f; unsigned u; } v; v.f = f;
    unsigned r = v.u + 0x7FFFu + ((v.u >> 16) & 1u);   // round-nearest-even
    return (short)(r >> 16);
}

__device__ __forceinline__ float fast_sigmoid(float v) {
    return __builtin_amdgcn_rcpf(1.0f + __expf(-v));
}
__device__ __forceinline__ float fast_softplus(float v) {
    float t = __expf(-fabsf(v));
    return fmaxf(v, 0.0f) + __logf(1.0f + t);
}

// prologue: x (f32, [N][32]) -> xb (bf16, [N][32]); one thread per 8 elems
__global__ __launch_bounds__(256) void xconv_kernel(
    const float* __restrict__ x, short* __restrict__ xb, int ngroups)
{
    const int i = blockIdx.x * 256 + threadIdx.x;
    if (i >= ngroups) return;
    const float4* p = (const float4*)x + 2 * (size_t)i;
    float4 u0 = p[0], u1 = p[1];
    bf16x8 o;
    o[0]=f2bf(u0.x); o[1]=f2bf(u0.y); o[2]=f2bf(u0.z); o[3]=f2bf(u0.w);
    o[4]=f2bf(u1.x); o[5]=f2bf(u1.y); o[6]=f2bf(u1.z); o[7]=f2bf(u1.w);
    ((bf16x8*)xb)[i] = o;
}

// Barrier-free edge kernel; wave-private LDS for ea staging (same-wave LDS
// ops execute in order -> no sync needed). agg accumulated via packed-f16
// atomics (global_atomic_pk_add_f16): half the atomic dwords of f32.
__global__ __launch_bounds__(256, 4) void edge_kernel(
    const short* __restrict__ xb,   // bf16 node features
    const int*   __restrict__ ei,
    const float* __restrict__ ea,
    const float* __restrict__ ew,
    const float* __restrict__ Wf,
    const float* __restrict__ bfb,
    const float* __restrict__ Ws,
    const float* __restrict__ bsb,
    __half2* __restrict__ agg2,   // [N][16] packed col pairs
    float* __restrict__ out_ei,   // harness reads whole d_out as f32
    float* __restrict__ out_ea,
    float* __restrict__ out_ew,
    int E)
{
    __shared__ short sea[4][WPC * EDGE_DIM];   // 2KB per wave, wave-private

    const int tid  = threadIdx.x;
    const int lane = tid & 63;
    const int wave = tid >> 6;
    const int kg   = lane >> 4;    // 0..3: k-slice group (8 bf16 each)
    const int c16  = lane & 15;    // fragment row/col index

    // ---- B fragments, column-pair-interleaved mapping ----
    // ct0: gate col 2*c16   ct1: gate col 2*c16+1
    // ct2: val  col 2*c16   ct3: val  col 2*c16+1
    // lane holds B[k = 32m + 8*kg + j][frag col c16], j=0..7 (k>=80 zero)
    bf16x8 Bf[3][4];
    float biasv[4];
    #pragma unroll
    for (int ct = 0; ct < 4; ++ct) {
        const float* Wsrc = (ct < 2) ? Wf  : Ws;
        const float* bsrc = (ct < 2) ? bfb : bsb;
        const int ccc = 2 * c16 + (ct & 1);        // 0..31
        biasv[ct] = bsrc[ccc];
        #pragma unroll
        for (int m = 0; m < 3; ++m) {
            bf16x8 frag;
            #pragma unroll
            for (int j = 0; j < 8; ++j) {
                const int k = 32 * m + 8 * kg + j;
                const float wv = (k < 80) ? Wsrc[k * NODE_DIM + ccc] : 0.0f;
                frag[j] = f2bf(wv);
            }
            Bf[m][ct] = frag;
        }
    }

    const int wid    = blockIdx.x * 4 + wave;
    const int nwaves = gridDim.x * 4;

    for (int base = wid * WPC; base < E; base += nwaves * WPC) {
        // ---- per-wave phase 1: meta into registers + passthrough + ea->LDS ----
        const int e0 = base + lane;
        int srcv = 0, dstv = -1; float wv = 0.0f;
        if (e0 < E) {
            srcv = ei[e0];
            dstv = ei[E + e0];
            wv   = ew[e0];
            out_ei[e0]     = (float)srcv;
            out_ei[E + e0] = (float)dstv;
            out_ew[e0]     = wv;
        }
        {
            const float4* s4 = (const float4*)ea;
            float4*       d4 = (float4*)out_ea;
            const int fmax = E * 4;          // total float4 count (E*16 floats)
            const int fb   = base * 4;
            #pragma unroll
            for (int t = 0; t < 4; ++t) {
                const int idx = fb + t * 64 + lane;
                if (idx < fmax) {
                    float4 v = s4[idx];
                    d4[idx] = v;
                    short4v sv = { f2bf(v.x), f2bf(v.y), f2bf(v.z), f2bf(v.w) };
                    *(short4v*)&sea[wave][(t * 64 + lane) * 4] = sv;
                }
            }
        }

        // ---- per-wave phase 2: 4 groups of 16 edges; MFMA z@[Wf|Ws] ----
        #pragma unroll 2
        for (int g = 0; g < 4; ++g) {
            const int sA   = g * 16 + c16;                 // A row m = c16
            const int dstn = max(__shfl(dstv, sA), 0);
            const int srcn = max(__shfl(srcv, sA), 0);

            // A0: z[0..31] = x[dst]; lane covers k = 8*kg..+7 (one 16B load)
            bf16x8 a0 = *(const bf16x8*)(xb + (size_t)dstn * NODE_DIM + 8 * kg);
            // A1: z[32..63] = x[src]
            bf16x8 a1 = *(const bf16x8*)(xb + (size_t)srcn * NODE_DIM + 8 * kg);
            // A2: z[64..95] = edge_attr | zero pad, from wave-private LDS
            bf16x8 a2 = {0,0,0,0,0,0,0,0};
            if (kg < 2) {
                a2 = *(const bf16x8*)&sea[wave][sA * EDGE_DIM + 8 * kg];
            }

            f32x4 acc0 = {biasv[0], biasv[0], biasv[0], biasv[0]};
            f32x4 acc1 = {biasv[1], biasv[1], biasv[1], biasv[1]};
            f32x4 acc2 = {biasv[2], biasv[2], biasv[2], biasv[2]};
            f32x4 acc3 = {biasv[3], biasv[3], biasv[3], biasv[3]};

            acc0 = __builtin_amdgcn_mfma_f32_16x16x32_bf16(a0, Bf[0][0], acc0, 0, 0, 0);
            acc1 = __builtin_amdgcn_mfma_f32_16x16x32_bf16(a0, Bf[0][1], acc1, 0, 0, 0);
            acc2 = __builtin_amdgcn_mfma_f32_16x16x32_bf16(a0, Bf[0][2], acc2, 0, 0, 0);
            acc3 = __builtin_amdgcn_mfma_f32_16x16x32_bf16(a0, Bf[0][3], acc3, 0, 0, 0);
            acc0 = __builtin_amdgcn_mfma_f32_16x16x32_bf16(a1, Bf[1][0], acc0, 0, 0, 0);
            acc1 = __builtin_amdgcn_mfma_f32_16x16x32_bf16(a1, Bf[1][1], acc1, 0, 0, 0);
            acc2 = __builtin_amdgcn_mfma_f32_16x16x32_bf16(a1, Bf[1][2], acc2, 0, 0, 0);
            acc3 = __builtin_amdgcn_mfma_f32_16x16x32_bf16(a1, Bf[1][3], acc3, 0, 0, 0);
            acc0 = __builtin_amdgcn_mfma_f32_16x16x32_bf16(a2, Bf[2][0], acc0, 0, 0, 0);
            acc1 = __builtin_amdgcn_mfma_f32_16x16x32_bf16(a2, Bf[2][1], acc1, 0, 0, 0);
            acc2 = __builtin_amdgcn_mfma_f32_16x16x32_bf16(a2, Bf[2][2], acc2, 0, 0, 0);
            acc3 = __builtin_amdgcn_mfma_f32_16x16x32_bf16(a2, Bf[2][3], acc3, 0, 0, 0);

            // C/D: row = kg*4 + r (rows = edges); lane's cols = (2*c16, 2*c16+1)
            const int rb = g * 16 + (kg << 2);
            #pragma unroll
            for (int r = 0; r < 4; ++r) {
                const int slot = rb + r;
                const int d    = __shfl(dstv, slot);
                const float w  = __shfl(wv,   slot);
                const float me = w * fast_sigmoid(acc0[r]) * fast_softplus(acc2[r]);
                const float mo = w * fast_sigmoid(acc1[r]) * fast_softplus(acc3[r]);
                if (d >= 0) {
                    __half2 hv = __floats2half2_rn(me, mo);
                    unsafeAtomicAdd(&agg2[(size_t)d * 16 + c16], hv);
                }
            }
        }
    }
}

__global__ __launch_bounds__(256) void node_kernel(
    const float* __restrict__ x,
    const __half2* __restrict__ agg2,
    const float* __restrict__ ln_g,
    const float* __restrict__ ln_b,
    const float* __restrict__ W,
    const float* __restrict__ b,
    float* __restrict__ out,
    int N)
{
    const int n = blockIdx.x * blockDim.x + threadIdx.x;
    if (n >= N) return;

    float xr[NODE_DIM], h[NODE_DIM];
    const float4*  xp = (const float4*)(x + (size_t)n * NODE_DIM);
    const __half2* ah = agg2 + (size_t)n * 16;

    float s = 0.0f, ss = 0.0f;
    #pragma unroll
    for (int i = 0; i < 8; ++i) {
        float4 xv = xp[i];
        float2 f0 = __half22float2(ah[2 * i]);
        float2 f1 = __half22float2(ah[2 * i + 1]);
        float hv0 = xv.x + f0.x, hv1 = xv.y + f0.y, hv2 = xv.z + f1.x, hv3 = xv.w + f1.y;
        xr[4*i+0] = xv.x; xr[4*i+1] = xv.y; xr[4*i+2] = xv.z; xr[4*i+3] = xv.w;
        h[4*i+0] = hv0; h[4*i+1] = hv1; h[4*i+2] = hv2; h[4*i+3] = hv3;
        s  += hv0 + hv1 + hv2 + hv3;
        ss += hv0*hv0 + hv1*hv1 + hv2*hv2 + hv3*hv3;
    }

    const float mu  = s * (1.0f / NODE_DIM);
    float var = ss * (1.0f / NODE_DIM) - mu * mu;
    var = fmaxf(var, 0.0f);
    const float rstd = __builtin_amdgcn_rsqf(var + 1e-5f);

    float acc[NODE_DIM];
    #pragma unroll
    for (int j = 0; j < NODE_DIM; ++j) acc[j] = b[j] + xr[j];

    #pragma unroll
    for (int k = 0; k < NODE_DIM; ++k) {
        float hn = (h[k] - mu) * rstd * ln_g[k] + ln_b[k];
        #pragma unroll
        for (int j = 0; j < NODE_DIM; ++j) {
            acc[j] = fmaf(hn, W[k * NODE_DIM + j], acc[j]);
        }
    }

    float4* op = (float4*)(out + (size_t)n * NODE_DIM);
    #pragma unroll
    for (int i = 0; i < 8; ++i) {
        float4 o;
        float a0 = acc[4*i+0], a1 = acc[4*i+1], a2 = acc[4*i+2], a3 = acc[4*i+3];
        o.x = (a0 > 0.0f) ? a0 : (__expf(a0) - 1.0f);
        o.y = (a1 > 0.0f) ? a1 : (__expf(a1) - 1.0f);
        o.z = (a2 > 0.0f) ? a2 : (__expf(a2) - 1.0f);
        o.w = (a3 > 0.0f) ? a3 : (__expf(a3) - 1.0f);
        op[i] = o;
    }
}

extern "C" void kernel_launch(void* const* d_in, const int* in_sizes, int n_in,
                              void* d_out, int out_size, void* d_ws, size_t ws_size,
                              hipStream_t stream)
{
    const float* x   = (const float*)d_in[0];
    const int*   ei  = (const int*)  d_in[1];
    const float* ea  = (const float*)d_in[2];
    const float* ew  = (const float*)d_in[3];
    const float* Wf  = (const float*)d_in[4];
    const float* bf  = (const float*)d_in[5];
    const float* Ws  = (const float*)d_in[6];
    const float* bs  = (const float*)d_in[7];
    const float* lg  = (const float*)d_in[8];
    const float* lb  = (const float*)d_in[9];
    const float* W   = (const float*)d_in[10];
    const float* b   = (const float*)d_in[11];

    const int E = in_sizes[3];              // N_EDGES
    const int N = in_sizes[0] / NODE_DIM;   // N_NODES

    float* out    = (float*)d_out;
    float* out_x  = out;
    float* out_ei = out + (size_t)N * NODE_DIM;
    float* out_ea = out + (size_t)N * NODE_DIM + 2 * (size_t)E;
    float* out_ew = out_ea + (size_t)E * EDGE_DIM;

    // workspace: agg2 (N*16 half2 = 6.4 MB) | xb (N*32 bf16 = 6.4 MB)
    __half2* agg2 = (__half2*)d_ws;
    short*   xbuf = (short*)((char*)d_ws + (size_t)N * 16 * sizeof(__half2));

    hipMemsetAsync(agg2, 0, (size_t)N * 16 * sizeof(__half2), stream);

    const int ngroups = N * NODE_DIM / 8;
    xconv_kernel<<<dim3((ngroups + 255) / 256), dim3(256), 0, stream>>>(x, xbuf, ngroups);

    int nblk = (E + 4 * WPC - 1) / (4 * WPC);
    if (nblk > MAXBLK) nblk = MAXBLK;
    edge_kernel<<<dim3(nblk), dim3(256), 0, stream>>>(
        xbuf, ei, ea, ew, Wf, bf, Ws, bs, agg2, out_ei, out_ea, out_ew, E);

    dim3 nb(256), ng((N + 255) / 256);
    node_kernel<<<ng, nb, 0, stream>>>(x, agg2, lg, lb, W, b, out_x, N);
}